// Round 2
// baseline (7668.448 us; speedup 1.0000x reference)
//
#include <hip/hip_runtime.h>

#define BB 256
#define TT 256
#define II 512
#define HH 1024

typedef _Float16 h16;
typedef __attribute__((ext_vector_type(4))) _Float16 h16x4;
typedef __attribute__((ext_vector_type(8))) _Float16 h16x8;
typedef __attribute__((ext_vector_type(4))) float f32x4;
typedef __attribute__((ext_vector_type(4))) unsigned int u32x4;

#define KPADH 1032
#define SMEM_BYTES 149504  // 64*1032*2 (Abuf) + 4*64*17*4 (Pre)

// workspace layout (bytes)
#define WX_OFF   0UL
#define WH_OFF   4194304UL
#define BIAS_OFF 12582912UL
#define W1T_OFF  12599296UL
#define HBUF_OFF 12861440UL
#define ARR_OFF  13385728UL
#define XH_OFF   13389824UL
#define XH_END   80498688UL

__device__ __forceinline__ float sigm(float x) { return 1.0f / (1.0f + __expf(-x)); }
__device__ __forceinline__ float tanh_(float x) { float e = __expf(2.0f * x); return 1.0f - 2.0f / (e + 1.0f); }

// ---------------- prep: cast/pack weights ----------------
__global__ void k_prep(const float* __restrict__ Wfx, const float* __restrict__ Wfh, const float* __restrict__ bf,
                       const float* __restrict__ Wix, const float* __restrict__ Wih, const float* __restrict__ bi,
                       const float* __restrict__ Wox, const float* __restrict__ Woh, const float* __restrict__ bo,
                       const float* __restrict__ Wcx, const float* __restrict__ Wch, const float* __restrict__ bc,
                       const float* __restrict__ W1,
                       h16* __restrict__ Wx, h16* __restrict__ Wh, float* __restrict__ bias, float* __restrict__ W1T)
{
  const long NWX = 4096L * 512, NWH = 4096L * 1024, NB = 4096, NW1 = 1024L * 64;
  const long total = NWX + NWH + NB + NW1;
  for (long id = blockIdx.x * 256L + threadIdx.x; id < total; id += gridDim.x * 256L) {
    if (id < NWX) {
      long n = id >> 9, k = id & 511;
      long g = n >> 10, j = n & 1023;
      const float* s = (g == 0) ? Wfx : (g == 1) ? Wix : (g == 2) ? Wox : Wcx;
      Wx[id] = (h16)s[j * II + k];
    } else if (id < NWX + NWH) {
      long i2 = id - NWX;
      long n = i2 >> 10, k = i2 & 1023;
      long g = n >> 10, j = n & 1023;
      const float* s = (g == 0) ? Wfh : (g == 1) ? Wih : (g == 2) ? Woh : Wch;
      Wh[i2] = (h16)s[j * HH + k];
    } else if (id < NWX + NWH + NB) {
      long n = id - NWX - NWH;
      long g = n >> 10, j = n & 1023;
      const float* s = (g == 0) ? bf : (g == 1) ? bi : (g == 2) ? bo : bc;
      bias[n] = s[j];
    } else {
      long i2 = id - NWX - NWH - NB;
      long k = i2 >> 6, n = i2 & 63;
      W1T[i2] = W1[n * HH + k];
    }
  }
}

// ---------------- prep: cast x to fp16 ----------------
__global__ void k_castx(const float* __restrict__ x, h16* __restrict__ xh) {
  const long n = (long)BB * TT * II;
  for (long i = (blockIdx.x * 256L + threadIdx.x) * 4; i < n; i += gridDim.x * 1024L) {
    float4 v = *(const float4*)(x + i);
    h16x4 o = {(h16)v.x, (h16)v.y, (h16)v.z, (h16)v.w};
    *(h16x4*)(xh + i) = o;
  }
}

// ---------------- persistent LSTM kernel ----------------
// grid 256 WGs x 512 thr (8 waves). 4 groups x 64 rows; per WG: 16 H-cols x 4 gates.
// 146KB LDS forces 1 WG/CU -> all 256 co-resident -> group barriers safe.
// Coherence protocol (no cache-invalidating fences!):
//   writers store h with sc0 sc1 (write-through to IC), drain vmcnt, syncthreads,
//   tid0 release-adds the step flag (agent scope, executes at IC).
//   readers poll flag (relaxed agent = sc1 load), then read h with sc0 sc1
//   (bypasses possibly-stale L1/L2, reads IC). Wh/Wx/x stay L2-resident forever.
template <int USE_XH>
__global__ __launch_bounds__(512, 1) void k_lstm(
    const float* __restrict__ x32, const h16* __restrict__ x16,
    const h16* __restrict__ Wx, const h16* __restrict__ Wh,
    const float* __restrict__ bias,
    h16* __restrict__ hbuf, unsigned int* __restrict__ arr)
{
  extern __shared__ char smem[];
  h16* Abuf = (h16*)smem;               // [64][KPADH] fp16
  float* Pre = (float*)(smem + 132096); // [4][64][17] f32

  const int tid = threadIdx.x;
  const int wid = tid >> 6;   // 0..7
  const int lane = tid & 63;
  const int lm = lane & 15;   // MFMA row/col within 16
  const int lq = lane >> 4;   // k-quad

  const int bx = blockIdx.x;
  const int idx = bx >> 3;
  const int nslice = (bx & 7) * 8 + (idx & 7);  // XCD-affinity swizzle (perf only)
  const int group = idx >> 3;                   // 0..3
  const int r0 = group * 64;
  const int hc0 = nslice * 16;

  const int mq = (wid & 3) * 16;      // row quarter 0/16/32/48
  const int gpair = (wid >> 2) * 2;   // gates {0,1} or {2,3}

  const h16* WhB[2]; const h16* WxB[2]; float bsv[2];
#pragma unroll
  for (int nt = 0; nt < 2; ++nt) {
    int ng = (gpair + nt) * HH + hc0 + lm;   // row of packed [4096 x K] weight
    WhB[nt] = Wh + (size_t)ng * HH + lq * 8;
    WxB[nt] = Wx + (size_t)ng * II + lq * 8;
    bsv[nt] = bias[ng];
  }
  const size_t xrow = (size_t)(r0 + mq + lm);
  const float* xr32 = x32 + xrow * ((size_t)TT * II) + lq * 8;
  const h16* xr16 = x16 + xrow * ((size_t)TT * II) + lq * 8;
  const int aBaseH = (mq + lm) * KPADH + lq * 8;

  const int urow = tid >> 3;        // 0..63
  const int ucolp = (tid & 7) * 2;  // 0,2,..,14
  float cst[2] = {0.f, 0.f};

  unsigned int* flag = arr + group * TT;

  for (int t = 0; t < TT; ++t) {
    f32x4 acc[2];
#pragma unroll
    for (int nt = 0; nt < 2; ++nt)
      acc[nt] = (f32x4){bsv[nt], bsv[nt], bsv[nt], bsv[nt]};

    // ---- x-part (independent of h; runs before the barrier wait) ----
#pragma unroll 4
    for (int kk = 0; kk < II / 32; ++kk) {
      h16x8 a0;
      if (USE_XH) {
        a0 = *(const h16x8*)(xr16 + (size_t)t * II + kk * 32);
      } else {
        const float* p0 = xr32 + (size_t)t * II + kk * 32;
        float4 u0 = *(const float4*)(p0), v0 = *(const float4*)(p0 + 4);
        a0 = (h16x8){(h16)u0.x, (h16)u0.y, (h16)u0.z, (h16)u0.w, (h16)v0.x, (h16)v0.y, (h16)v0.z, (h16)v0.w};
      }
      h16x8 b0 = *(const h16x8*)(WxB[0] + kk * 32);
      h16x8 b1 = *(const h16x8*)(WxB[1] + kk * 32);
      acc[0] = __builtin_amdgcn_mfma_f32_16x16x32_f16(a0, b0, acc[0], 0, 0, 0);
      acc[1] = __builtin_amdgcn_mfma_f32_16x16x32_f16(a0, b1, acc[1], 0, 0, 0);
    }

    if (t > 0) {
      // ---- group barrier: wait for h(t-1) (no cache-invalidating fence) ----
      if (tid == 0) {
        while (__hip_atomic_load(flag + (t - 1), __ATOMIC_RELAXED, __HIP_MEMORY_SCOPE_AGENT) < 64u)
          __builtin_amdgcn_s_sleep(1);
      }
      __syncthreads();
      // ---- stage h(t-1) -> LDS via system-coherent loads (read IC directly) ----
      {
        const h16* hs = hbuf + (size_t)r0 * HH;
        u32x4 tmp[16];
#pragma unroll
        for (int j = 0; j < 16; ++j) {
          int c = tid + j * 512;              // 0..8191
          int r = c >> 7, col = c & 127;
          const h16* p = hs + (size_t)r * HH + col * 8;
          asm volatile("global_load_dwordx4 %0, %1, off sc0 sc1"
                       : "=v"(tmp[j]) : "v"(p) : "memory");
        }
        asm volatile("s_waitcnt vmcnt(0)" ::: "memory");
#pragma unroll
        for (int j = 0; j < 16; ++j) {
          int c = tid + j * 512;
          int r = c >> 7, col = c & 127;
          *(u32x4*)(Abuf + r * KPADH + col * 8) = tmp[j];
        }
      }
      __syncthreads();
      // ---- h-part GEMM (A from LDS, B hot in L2) ----
#pragma unroll 4
      for (int kk = 0; kk < HH / 32; ++kk) {
        h16x8 a0 = *(const h16x8*)(Abuf + aBaseH + kk * 32);
        h16x8 b0 = *(const h16x8*)(WhB[0] + kk * 32);
        h16x8 b1 = *(const h16x8*)(WhB[1] + kk * 32);
        acc[0] = __builtin_amdgcn_mfma_f32_16x16x32_f16(a0, b0, acc[0], 0, 0, 0);
        acc[1] = __builtin_amdgcn_mfma_f32_16x16x32_f16(a0, b1, acc[1], 0, 0, 0);
      }
    }

    // ---- epilogue: preacts -> LDS (cross-wave gate exchange) ----
#pragma unroll
    for (int nt = 0; nt < 2; ++nt) {
      int gate = gpair + nt;
#pragma unroll
      for (int i = 0; i < 4; ++i) {
        int row = mq + lq * 4 + i;
        Pre[(gate * 64 + row) * 17 + lm] = acc[nt][i];
      }
    }
    __syncthreads();
    // ---- elementwise c/h update (c persistent in regs), write-through h ----
    {
      float hv[2];
#pragma unroll
      for (int cc = 0; cc < 2; ++cc) {
        int col = ucolp + cc;
        float fp = Pre[(0 * 64 + urow) * 17 + col];
        float ip = Pre[(1 * 64 + urow) * 17 + col];
        float op = Pre[(2 * 64 + urow) * 17 + col];
        float cp = Pre[(3 * 64 + urow) * 17 + col];
        float c2 = sigm(fp) * cst[cc] + sigm(ip) * tanh_(cp);
        cst[cc] = c2;
        hv[cc] = sigm(op) * tanh_(c2);
      }
      union { h16 h[2]; unsigned int u; } pk;
      pk.h[0] = (h16)hv[0]; pk.h[1] = (h16)hv[1];
      const h16* hp = hbuf + (size_t)(r0 + urow) * HH + hc0 + ucolp;
      asm volatile("global_store_dword %0, %1, off sc0 sc1"
                   :: "v"(hp), "v"(pk.u) : "memory");
    }
    __builtin_amdgcn_s_waitcnt(0);
    __syncthreads();  // all waves' h stores drained (in IC) before release
    if (tid == 0)
      __hip_atomic_fetch_add(flag + t, 1u, __ATOMIC_RELEASE, __HIP_MEMORY_SCOPE_AGENT);
  }
}

// ---------------- head: relu -> [64] relu -> [10] softmax ----------------
__global__ void k_head(const h16* __restrict__ hbuf, const float* __restrict__ W1T,
                       const float* __restrict__ b1, const float* __restrict__ W2,
                       const float* __restrict__ b2, float* __restrict__ out)
{
  __shared__ float hrow[1024];
  __shared__ float part[64][5];
  __shared__ float h1[64];
  __shared__ float logit[10];
  int r = blockIdx.x, tid = threadIdx.x;
  for (int i = tid; i < 1024; i += 256) {
    float v = (float)hbuf[(size_t)r * HH + i];
    hrow[i] = v > 0.f ? v : 0.f;
  }
  __syncthreads();
  int n = tid & 63, q = tid >> 6;
  float s = 0.f;
  for (int i = 0; i < 256; ++i) s += hrow[q * 256 + i] * W1T[(q * 256 + i) * 64 + n];
  part[n][q] = s;
  __syncthreads();
  if (tid < 64) {
    float v = part[tid][0] + part[tid][1] + part[tid][2] + part[tid][3] + b1[tid];
    h1[tid] = v > 0.f ? v : 0.f;
  }
  __syncthreads();
  if (tid < 10) {
    float s2 = b2[tid];
    for (int k = 0; k < 64; ++k) s2 += h1[k] * W2[tid * 64 + k];
    logit[tid] = s2;
  }
  __syncthreads();
  if (tid < 10) {
    float m = logit[0];
    for (int i = 1; i < 10; ++i) m = fmaxf(m, logit[i]);
    float sum = 0.f;
    for (int i = 0; i < 10; ++i) sum += __expf(logit[i] - m);
    out[r * 10 + tid] = __expf(logit[tid] - m) / sum;
  }
}

extern "C" void kernel_launch(void* const* d_in, const int* in_sizes, int n_in,
                              void* d_out, int out_size, void* d_ws, size_t ws_size,
                              hipStream_t stream) {
  const float* x   = (const float*)d_in[0];
  const float* Wfx = (const float*)d_in[1];
  const float* Wfh = (const float*)d_in[2];
  const float* bf  = (const float*)d_in[3];
  const float* Wix = (const float*)d_in[4];
  const float* Wih = (const float*)d_in[5];
  const float* bi  = (const float*)d_in[6];
  const float* Wox = (const float*)d_in[7];
  const float* Woh = (const float*)d_in[8];
  const float* bo  = (const float*)d_in[9];
  const float* Wcx = (const float*)d_in[10];
  const float* Wch = (const float*)d_in[11];
  const float* bc  = (const float*)d_in[12];
  const float* W1  = (const float*)d_in[13];
  const float* b1  = (const float*)d_in[14];
  const float* W2  = (const float*)d_in[15];
  const float* b2  = (const float*)d_in[16];
  (void)in_sizes; (void)n_in; (void)out_size;

  char* ws = (char*)d_ws;
  h16* Wx = (h16*)(ws + WX_OFF);
  h16* Wh = (h16*)(ws + WH_OFF);
  float* bias = (float*)(ws + BIAS_OFF);
  float* W1T = (float*)(ws + W1T_OFF);
  h16* hbuf = (h16*)(ws + HBUF_OFF);
  unsigned int* arr = (unsigned int*)(ws + ARR_OFF);
  h16* xh = (h16*)(ws + XH_OFF);
  const int use_xh = (ws_size >= XH_END) ? 1 : 0;

  hipMemsetAsync(arr, 0, 4096, stream);
  k_prep<<<4096, 256, 0, stream>>>(Wfx, Wfh, bf, Wix, Wih, bi, Wox, Woh, bo, Wcx, Wch, bc, W1,
                                   Wx, Wh, bias, W1T);
  if (use_xh) k_castx<<<8192, 256, 0, stream>>>(x, xh);

  (void)hipFuncSetAttribute(reinterpret_cast<const void*>(&k_lstm<1>),
                            hipFuncAttributeMaxDynamicSharedMemorySize, SMEM_BYTES);
  (void)hipFuncSetAttribute(reinterpret_cast<const void*>(&k_lstm<0>),
                            hipFuncAttributeMaxDynamicSharedMemorySize, SMEM_BYTES);
  if (use_xh)
    k_lstm<1><<<256, 512, SMEM_BYTES, stream>>>(x, xh, Wx, Wh, bias, hbuf, arr);
  else
    k_lstm<0><<<256, 512, SMEM_BYTES, stream>>>(x, xh, Wx, Wh, bias, hbuf, arr);

  k_head<<<256, 256, 0, stream>>>(hbuf, W1T, b1, W2, b2, (float*)d_out);
}

// Round 3
// 7339.445 us; speedup vs baseline: 1.0448x; 1.0448x over previous
//
#include <hip/hip_runtime.h>

#define BB 256
#define TT 256
#define II 512
#define HH 1024

typedef _Float16 h16;
typedef __attribute__((ext_vector_type(4))) _Float16 h16x4;
typedef __attribute__((ext_vector_type(8))) _Float16 h16x8;
typedef __attribute__((ext_vector_type(4))) float f32x4;
typedef __attribute__((ext_vector_type(4))) unsigned int u32x4;

#define KPADH 1032
#define SMEM_BYTES 149504  // 64*1032*2 (Abuf) + 4*64*17*4 (Pre)

// workspace layout (bytes)
#define WX_OFF   0UL
#define WH_OFF   4194304UL
#define BIAS_OFF 12582912UL
#define W1T_OFF  12599296UL
#define HBUF_OFF 12861440UL
#define ARR_OFF  13385728UL
#define XH_OFF   13389824UL
#define XH_END   80498688UL

__device__ __forceinline__ float sigm(float x) { return 1.0f / (1.0f + __expf(-x)); }
__device__ __forceinline__ float tanh_(float x) { float e = __expf(2.0f * x); return 1.0f - 2.0f / (e + 1.0f); }

// ---------------- prep: cast/pack weights ----------------
__global__ void k_prep(const float* __restrict__ Wfx, const float* __restrict__ Wfh, const float* __restrict__ bf,
                       const float* __restrict__ Wix, const float* __restrict__ Wih, const float* __restrict__ bi,
                       const float* __restrict__ Wox, const float* __restrict__ Woh, const float* __restrict__ bo,
                       const float* __restrict__ Wcx, const float* __restrict__ Wch, const float* __restrict__ bc,
                       const float* __restrict__ W1,
                       h16* __restrict__ Wx, h16* __restrict__ Wh, float* __restrict__ bias, float* __restrict__ W1T)
{
  const long NWX = 4096L * 512, NWH = 4096L * 1024, NB = 4096, NW1 = 1024L * 64;
  const long total = NWX + NWH + NB + NW1;
  for (long id = blockIdx.x * 256L + threadIdx.x; id < total; id += gridDim.x * 256L) {
    if (id < NWX) {
      long n = id >> 9, k = id & 511;
      long g = n >> 10, j = n & 1023;
      const float* s = (g == 0) ? Wfx : (g == 1) ? Wix : (g == 2) ? Wox : Wcx;
      Wx[id] = (h16)s[j * II + k];
    } else if (id < NWX + NWH) {
      long i2 = id - NWX;
      long n = i2 >> 10, k = i2 & 1023;
      long g = n >> 10, j = n & 1023;
      const float* s = (g == 0) ? Wfh : (g == 1) ? Wih : (g == 2) ? Woh : Wch;
      Wh[i2] = (h16)s[j * HH + k];
    } else if (id < NWX + NWH + NB) {
      long n = id - NWX - NWH;
      long g = n >> 10, j = n & 1023;
      const float* s = (g == 0) ? bf : (g == 1) ? bi : (g == 2) ? bo : bc;
      bias[n] = s[j];
    } else {
      long i2 = id - NWX - NWH - NB;
      long k = i2 >> 6, n = i2 & 63;
      W1T[i2] = W1[n * HH + k];
    }
  }
}

// ---------------- prep: cast x to fp16 ----------------
__global__ void k_castx(const float* __restrict__ x, h16* __restrict__ xh) {
  const long n = (long)BB * TT * II;
  for (long i = (blockIdx.x * 256L + threadIdx.x) * 4; i < n; i += gridDim.x * 1024L) {
    float4 v = *(const float4*)(x + i);
    h16x4 o = {(h16)v.x, (h16)v.y, (h16)v.z, (h16)v.w};
    *(h16x4*)(xh + i) = o;
  }
}

// ---------------- persistent LSTM kernel ----------------
// grid 256 WGs x 512 thr (8 waves). 4 groups x 64 rows; per WG: 16 H-cols x 4 gates.
// 146KB LDS forces 1 WG/CU -> all 256 co-resident.
// Sync protocol: ZERO atomics, ZERO cache-maintenance ops in the hot loop.
//   Producer: h stores sc0 sc1 (write-through, complete at IC) -> s_waitcnt(0)
//   -> syncthreads -> plain sc0 sc1 STORE of (t+1) to its own per-WG slot.
//   Consumer: wave0 polls the 64 slots of its group with one 256B wave-wide
//   sc0 sc1 load + __any; slot visibility at IC implies h visibility at IC
//   (h stores were drained before the slot store was issued).
//   No RMW -> no buffer_wbl2/buffer_inv -> L2 stays hot for Wx/Wh/x.
template <int USE_XH>
__global__ __launch_bounds__(512, 1) void k_lstm(
    const float* __restrict__ x32, const h16* __restrict__ x16,
    const h16* __restrict__ Wx, const h16* __restrict__ Wh,
    const float* __restrict__ bias,
    h16* __restrict__ hbuf, unsigned int* __restrict__ arr)
{
  extern __shared__ char smem[];
  h16* Abuf = (h16*)smem;               // [64][KPADH] fp16
  float* Pre = (float*)(smem + 132096); // [4][64][17] f32

  const int tid = threadIdx.x;
  const int wid = tid >> 6;   // 0..7
  const int lane = tid & 63;
  const int lm = lane & 15;   // MFMA row/col within 16
  const int lq = lane >> 4;   // k-quad

  const int bx = blockIdx.x;
  const int idx = bx >> 3;
  const int nslice = (bx & 7) * 8 + (idx & 7);  // XCD-affinity swizzle; unique slot in group
  const int group = idx >> 3;                   // 0..3
  const int r0 = group * 64;
  const int hc0 = nslice * 16;

  const int mq = (wid & 3) * 16;      // row quarter 0/16/32/48
  const int gpair = (wid >> 2) * 2;   // gates {0,1} or {2,3}

  const h16* WhB[2]; const h16* WxB[2]; float bsv[2];
#pragma unroll
  for (int nt = 0; nt < 2; ++nt) {
    int ng = (gpair + nt) * HH + hc0 + lm;   // row of packed [4096 x K] weight
    WhB[nt] = Wh + (size_t)ng * HH + lq * 8;
    WxB[nt] = Wx + (size_t)ng * II + lq * 8;
    bsv[nt] = bias[ng];
  }
  const size_t xrow = (size_t)(r0 + mq + lm);
  const float* xr32 = x32 + xrow * ((size_t)TT * II) + lq * 8;
  const h16* xr16 = x16 + xrow * ((size_t)TT * II) + lq * 8;
  const int aBaseH = (mq + lm) * KPADH + lq * 8;

  const int urow = tid >> 3;        // 0..63
  const int ucolp = (tid & 7) * 2;  // 0,2,..,14
  float cst[2] = {0.f, 0.f};

  unsigned int* slots = arr + group * 64;   // 64 per-WG slots, 256B contiguous
  unsigned int* myslot = slots + nslice;

  for (int t = 0; t < TT; ++t) {
    f32x4 acc[2];
#pragma unroll
    for (int nt = 0; nt < 2; ++nt)
      acc[nt] = (f32x4){bsv[nt], bsv[nt], bsv[nt], bsv[nt]};

    // ---- x-part (independent of h; runs before the wait) ----
#pragma unroll 4
    for (int kk = 0; kk < II / 32; ++kk) {
      h16x8 a0;
      if (USE_XH) {
        a0 = *(const h16x8*)(xr16 + (size_t)t * II + kk * 32);
      } else {
        const float* p0 = xr32 + (size_t)t * II + kk * 32;
        float4 u0 = *(const float4*)(p0), v0 = *(const float4*)(p0 + 4);
        a0 = (h16x8){(h16)u0.x, (h16)u0.y, (h16)u0.z, (h16)u0.w, (h16)v0.x, (h16)v0.y, (h16)v0.z, (h16)v0.w};
      }
      h16x8 b0 = *(const h16x8*)(WxB[0] + kk * 32);
      h16x8 b1 = *(const h16x8*)(WxB[1] + kk * 32);
      acc[0] = __builtin_amdgcn_mfma_f32_16x16x32_f16(a0, b0, acc[0], 0, 0, 0);
      acc[1] = __builtin_amdgcn_mfma_f32_16x16x32_f16(a0, b1, acc[1], 0, 0, 0);
    }

    if (t > 0) {
      // ---- group barrier: wave0 polls all 64 producer slots (no atomics) ----
      if (tid < 64) {
        const unsigned int* sp = slots + tid;
        unsigned int v;
        do {
          asm volatile("global_load_dword %0, %1, off sc0 sc1\n\t"
                       "s_waitcnt vmcnt(0)"
                       : "=v"(v) : "v"(sp) : "memory");
        } while (__any(v < (unsigned int)t));
      }
      __syncthreads();
      // ---- stage h(t-1) -> LDS via IC-coherent loads ----
      {
        const h16* hs = hbuf + (size_t)r0 * HH;
        u32x4 tmp[16];
#pragma unroll
        for (int j = 0; j < 16; ++j) {
          int c = tid + j * 512;              // 0..8191
          int r = c >> 7, col = c & 127;
          const h16* p = hs + (size_t)r * HH + col * 8;
          asm volatile("global_load_dwordx4 %0, %1, off sc0 sc1"
                       : "=v"(tmp[j]) : "v"(p) : "memory");
        }
        asm volatile("s_waitcnt vmcnt(0)" ::: "memory");
#pragma unroll
        for (int j = 0; j < 16; ++j) {
          int c = tid + j * 512;
          int r = c >> 7, col = c & 127;
          *(u32x4*)(Abuf + r * KPADH + col * 8) = tmp[j];
        }
      }
      __syncthreads();
      // ---- h-part GEMM (A from LDS, B hot in L2) ----
#pragma unroll 4
      for (int kk = 0; kk < HH / 32; ++kk) {
        h16x8 a0 = *(const h16x8*)(Abuf + aBaseH + kk * 32);
        h16x8 b0 = *(const h16x8*)(WhB[0] + kk * 32);
        h16x8 b1 = *(const h16x8*)(WhB[1] + kk * 32);
        acc[0] = __builtin_amdgcn_mfma_f32_16x16x32_f16(a0, b0, acc[0], 0, 0, 0);
        acc[1] = __builtin_amdgcn_mfma_f32_16x16x32_f16(a0, b1, acc[1], 0, 0, 0);
      }
    }

    // ---- epilogue: preacts -> LDS (cross-wave gate exchange) ----
#pragma unroll
    for (int nt = 0; nt < 2; ++nt) {
      int gate = gpair + nt;
#pragma unroll
      for (int i = 0; i < 4; ++i) {
        int row = mq + lq * 4 + i;
        Pre[(gate * 64 + row) * 17 + lm] = acc[nt][i];
      }
    }
    __syncthreads();
    // ---- elementwise c/h update (c persistent in regs), write-through h ----
    {
      float hv[2];
#pragma unroll
      for (int cc = 0; cc < 2; ++cc) {
        int col = ucolp + cc;
        float fp = Pre[(0 * 64 + urow) * 17 + col];
        float ip = Pre[(1 * 64 + urow) * 17 + col];
        float op = Pre[(2 * 64 + urow) * 17 + col];
        float cp = Pre[(3 * 64 + urow) * 17 + col];
        float c2 = sigm(fp) * cst[cc] + sigm(ip) * tanh_(cp);
        cst[cc] = c2;
        hv[cc] = sigm(op) * tanh_(c2);
      }
      union { h16 h[2]; unsigned int u; } pk;
      pk.h[0] = (h16)hv[0]; pk.h[1] = (h16)hv[1];
      const h16* hp = hbuf + (size_t)(r0 + urow) * HH + hc0 + ucolp;
      asm volatile("global_store_dword %0, %1, off sc0 sc1"
                   :: "v"(hp), "v"(pk.u) : "memory");
    }
    __builtin_amdgcn_s_waitcnt(0);   // h stores complete (at IC; they bypass L2)
    __syncthreads();                 // ...for ALL waves of this WG
    if (tid == 0) {                  // now publish: plain store, no RMW, no wbl2
      unsigned int val = (unsigned int)(t + 1);
      asm volatile("global_store_dword %0, %1, off sc0 sc1"
                   :: "v"(myslot), "v"(val) : "memory");
    }
  }
}

// ---------------- head: relu -> [64] relu -> [10] softmax ----------------
__global__ void k_head(const h16* __restrict__ hbuf, const float* __restrict__ W1T,
                       const float* __restrict__ b1, const float* __restrict__ W2,
                       const float* __restrict__ b2, float* __restrict__ out)
{
  __shared__ float hrow[1024];
  __shared__ float part[64][5];
  __shared__ float h1[64];
  __shared__ float logit[10];
  int r = blockIdx.x, tid = threadIdx.x;
  for (int i = tid; i < 1024; i += 256) {
    float v = (float)hbuf[(size_t)r * HH + i];
    hrow[i] = v > 0.f ? v : 0.f;
  }
  __syncthreads();
  int n = tid & 63, q = tid >> 6;
  float s = 0.f;
  for (int i = 0; i < 256; ++i) s += hrow[q * 256 + i] * W1T[(q * 256 + i) * 64 + n];
  part[n][q] = s;
  __syncthreads();
  if (tid < 64) {
    float v = part[tid][0] + part[tid][1] + part[tid][2] + part[tid][3] + b1[tid];
    h1[tid] = v > 0.f ? v : 0.f;
  }
  __syncthreads();
  if (tid < 10) {
    float s2 = b2[tid];
    for (int k = 0; k < 64; ++k) s2 += h1[k] * W2[tid * 64 + k];
    logit[tid] = s2;
  }
  __syncthreads();
  if (tid < 10) {
    float m = logit[0];
    for (int i = 1; i < 10; ++i) m = fmaxf(m, logit[i]);
    float sum = 0.f;
    for (int i = 0; i < 10; ++i) sum += __expf(logit[i] - m);
    out[r * 10 + tid] = __expf(logit[tid] - m) / sum;
  }
}

extern "C" void kernel_launch(void* const* d_in, const int* in_sizes, int n_in,
                              void* d_out, int out_size, void* d_ws, size_t ws_size,
                              hipStream_t stream) {
  const float* x   = (const float*)d_in[0];
  const float* Wfx = (const float*)d_in[1];
  const float* Wfh = (const float*)d_in[2];
  const float* bf  = (const float*)d_in[3];
  const float* Wix = (const float*)d_in[4];
  const float* Wih = (const float*)d_in[5];
  const float* bi  = (const float*)d_in[6];
  const float* Wox = (const float*)d_in[7];
  const float* Woh = (const float*)d_in[8];
  const float* bo  = (const float*)d_in[9];
  const float* Wcx = (const float*)d_in[10];
  const float* Wch = (const float*)d_in[11];
  const float* bc  = (const float*)d_in[12];
  const float* W1  = (const float*)d_in[13];
  const float* b1  = (const float*)d_in[14];
  const float* W2  = (const float*)d_in[15];
  const float* b2  = (const float*)d_in[16];
  (void)in_sizes; (void)n_in; (void)out_size;

  char* ws = (char*)d_ws;
  h16* Wx = (h16*)(ws + WX_OFF);
  h16* Wh = (h16*)(ws + WH_OFF);
  float* bias = (float*)(ws + BIAS_OFF);
  float* W1T = (float*)(ws + W1T_OFF);
  h16* hbuf = (h16*)(ws + HBUF_OFF);
  unsigned int* arr = (unsigned int*)(ws + ARR_OFF);
  h16* xh = (h16*)(ws + XH_OFF);
  const int use_xh = (ws_size >= XH_END) ? 1 : 0;

  hipMemsetAsync(arr, 0, 4096, stream);
  k_prep<<<4096, 256, 0, stream>>>(Wfx, Wfh, bf, Wix, Wih, bi, Wox, Woh, bo, Wcx, Wch, bc, W1,
                                   Wx, Wh, bias, W1T);
  if (use_xh) k_castx<<<8192, 256, 0, stream>>>(x, xh);

  (void)hipFuncSetAttribute(reinterpret_cast<const void*>(&k_lstm<1>),
                            hipFuncAttributeMaxDynamicSharedMemorySize, SMEM_BYTES);
  (void)hipFuncSetAttribute(reinterpret_cast<const void*>(&k_lstm<0>),
                            hipFuncAttributeMaxDynamicSharedMemorySize, SMEM_BYTES);
  if (use_xh)
    k_lstm<1><<<256, 512, SMEM_BYTES, stream>>>(x, xh, Wx, Wh, bias, hbuf, arr);
  else
    k_lstm<0><<<256, 512, SMEM_BYTES, stream>>>(x, xh, Wx, Wh, bias, hbuf, arr);

  k_head<<<256, 256, 0, stream>>>(hbuf, W1T, b1, W2, b2, (float*)d_out);
}

// Round 5
// 4198.106 us; speedup vs baseline: 1.8266x; 1.7483x over previous
//
#include <hip/hip_runtime.h>

#define BB 256
#define TT 256
#define II 512
#define HH 1024

typedef _Float16 h16;
typedef __attribute__((ext_vector_type(4))) _Float16 h16x4;
typedef __attribute__((ext_vector_type(8))) _Float16 h16x8;
typedef __attribute__((ext_vector_type(4))) float f32x4;
typedef __attribute__((ext_vector_type(4))) unsigned int u32x4;

#define KPADH 1032
#define SMEM_BYTES 149504  // 64*1032*2 (Abuf) + 4*64*17*4 (Pre)

// workspace layout (bytes)
#define WX_OFF   0UL
#define WH_OFF   4194304UL
#define BIAS_OFF 12582912UL
#define W1T_OFF  12599296UL
#define HBUF_OFF 12861440UL      // 2 x 524288 (parity double buffer)
#define ARR_OFF  13910016UL
#define XH_OFF   13914112UL
#define XH_END   81022976UL

#define HSTRIDE (BB * HH)        // elements per hbuf parity buffer

__device__ __forceinline__ float sigm(float x) { return 1.0f / (1.0f + __expf(-x)); }
__device__ __forceinline__ float tanh_(float x) { float e = __expf(2.0f * x); return 1.0f - 2.0f / (e + 1.0f); }

// ---------------- prep: cast/pack weights ----------------
__global__ void k_prep(const float* __restrict__ Wfx, const float* __restrict__ Wfh, const float* __restrict__ bf,
                       const float* __restrict__ Wix, const float* __restrict__ Wih, const float* __restrict__ bi,
                       const float* __restrict__ Wox, const float* __restrict__ Woh, const float* __restrict__ bo,
                       const float* __restrict__ Wcx, const float* __restrict__ Wch, const float* __restrict__ bc,
                       const float* __restrict__ W1,
                       h16* __restrict__ Wx, h16* __restrict__ Wh, float* __restrict__ bias, float* __restrict__ W1T)
{
  const long NWX = 4096L * 512, NWH = 4096L * 1024, NB = 4096, NW1 = 1024L * 64;
  const long total = NWX + NWH + NB + NW1;
  for (long id = blockIdx.x * 256L + threadIdx.x; id < total; id += gridDim.x * 256L) {
    if (id < NWX) {
      long n = id >> 9, k = id & 511;
      long g = n >> 10, j = n & 1023;
      const float* s = (g == 0) ? Wfx : (g == 1) ? Wix : (g == 2) ? Wox : Wcx;
      Wx[id] = (h16)s[j * II + k];
    } else if (id < NWX + NWH) {
      long i2 = id - NWX;
      long n = i2 >> 10, k = i2 & 1023;
      long g = n >> 10, j = n & 1023;
      const float* s = (g == 0) ? Wfh : (g == 1) ? Wih : (g == 2) ? Woh : Wch;
      Wh[i2] = (h16)s[j * HH + k];
    } else if (id < NWX + NWH + NB) {
      long n = id - NWX - NWH;
      long g = n >> 10, j = n & 1023;
      const float* s = (g == 0) ? bf : (g == 1) ? bi : (g == 2) ? bo : bc;
      bias[n] = s[j];
    } else {
      long i2 = id - NWX - NWH - NB;
      long k = i2 >> 6, n = i2 & 63;
      W1T[i2] = W1[n * HH + k];
    }
  }
}

// ---------------- prep: cast x to fp16 ----------------
__global__ void k_castx(const float* __restrict__ x, h16* __restrict__ xh) {
  const long n = (long)BB * TT * II;
  for (long i = (blockIdx.x * 256L + threadIdx.x) * 4; i < n; i += gridDim.x * 1024L) {
    float4 v = *(const float4*)(x + i);
    h16x4 o = {(h16)v.x, (h16)v.y, (h16)v.z, (h16)v.w};
    *(h16x4*)(xh + i) = o;
  }
}

// ---------------- persistent LSTM kernel ----------------
// grid 256 WGs x 512 thr (8 waves). 4 groups x 64 rows; per WG: 16 H-cols x 4 gates.
// Wh fragments live in REGISTERS for the whole t-loop (128 VGPRs/wave).
// hbuf is PARITY DOUBLE-BUFFERED: step t writes h(t) to buf[t&1], step t+1
// stages from buf[t&1]; buf[t&1] is next overwritten at step t+2, which the
// slot-poll orders strictly after all WGs finished step t+1 (and hence their
// staging reads of h(t)). This closes the WAR race that round-4's faster
// GEMM exposed (rounds 1-3 masked it behind the 25us L2 Wh stream).
template <int USE_XH>
__global__ __launch_bounds__(512, 1) void k_lstm(
    const float* __restrict__ x32, const h16* __restrict__ x16,
    const h16* __restrict__ Wx, const h16* __restrict__ Wh,
    const float* __restrict__ bias,
    h16* __restrict__ hbuf, unsigned int* __restrict__ arr)
{
  extern __shared__ char smem[];
  h16* Abuf = (h16*)smem;               // [64][KPADH] fp16
  float* Pre = (float*)(smem + 132096); // [4][64][17] f32

  const int tid = threadIdx.x;
  const int wid = tid >> 6;   // 0..7
  const int lane = tid & 63;
  const int lm = lane & 15;   // MFMA row/col within 16
  const int lq = lane >> 4;   // k-quad

  const int bx = blockIdx.x;
  const int idx = bx >> 3;
  const int nslice = (bx & 7) * 8 + (idx & 7);  // XCD-affinity swizzle; unique slot in group
  const int group = idx >> 3;                   // 0..3
  const int r0 = group * 64;
  const int hc0 = nslice * 16;

  const int mh = (wid & 1) * 32;   // row half base: 0 / 32
  const int g = wid >> 1;          // gate 0..3

  const int ng = g * HH + hc0 + lm;           // row of packed [4096 x K] weight
  const float bsv = bias[ng];
  const h16* WxBp = Wx + (size_t)ng * II + lq * 8;

  // ---- load Wh fragments into registers ONCE (128 VGPRs, resident all steps) ----
  h16x8 wh[32];
  {
    const h16* whp = Wh + (size_t)ng * HH + lq * 8;
#pragma unroll
    for (int kk = 0; kk < 32; ++kk) wh[kk] = *(const h16x8*)(whp + kk * 32);
  }

  const size_t xrow0 = (size_t)(r0 + mh + lm);
  const float* xr32_0 = x32 + xrow0 * ((size_t)TT * II) + lq * 8;
  const float* xr32_1 = xr32_0 + 16 * ((size_t)TT * II);
  const h16* xr16_0 = x16 + xrow0 * ((size_t)TT * II) + lq * 8;
  const h16* xr16_1 = xr16_0 + 16 * ((size_t)TT * II);
  const int aBase0 = (mh + lm) * KPADH + lq * 8;
  const int aBase1 = (mh + 16 + lm) * KPADH + lq * 8;

  const int urow = tid >> 3;        // 0..63
  const int ucolp = (tid & 7) * 2;  // 0,2,..,14
  float cst[2] = {0.f, 0.f};

  unsigned int* slots = arr + group * 64;   // 64 per-WG slots, 256B contiguous
  unsigned int* myslot = slots + nslice;

  for (int t = 0; t < TT; ++t) {
    f32x4 acc[2];
    acc[0] = (f32x4){bsv, bsv, bsv, bsv};
    acc[1] = acc[0];

    // ---- x-part (independent of h; runs before the wait) ----
#pragma unroll 4
    for (int kk = 0; kk < II / 32; ++kk) {
      h16x8 a0, a1;
      if (USE_XH) {
        a0 = *(const h16x8*)(xr16_0 + (size_t)t * II + kk * 32);
        a1 = *(const h16x8*)(xr16_1 + (size_t)t * II + kk * 32);
      } else {
        const float* p0 = xr32_0 + (size_t)t * II + kk * 32;
        const float* p1 = xr32_1 + (size_t)t * II + kk * 32;
        float4 u0 = *(const float4*)(p0), v0 = *(const float4*)(p0 + 4);
        float4 u1 = *(const float4*)(p1), v1 = *(const float4*)(p1 + 4);
        a0 = (h16x8){(h16)u0.x, (h16)u0.y, (h16)u0.z, (h16)u0.w, (h16)v0.x, (h16)v0.y, (h16)v0.z, (h16)v0.w};
        a1 = (h16x8){(h16)u1.x, (h16)u1.y, (h16)u1.z, (h16)u1.w, (h16)v1.x, (h16)v1.y, (h16)v1.z, (h16)v1.w};
      }
      h16x8 b0 = *(const h16x8*)(WxBp + kk * 32);
      acc[0] = __builtin_amdgcn_mfma_f32_16x16x32_f16(a0, b0, acc[0], 0, 0, 0);
      acc[1] = __builtin_amdgcn_mfma_f32_16x16x32_f16(a1, b0, acc[1], 0, 0, 0);
    }

    if (t > 0) {
      // ---- group barrier: wave0 polls all 64 producer slots (no atomics) ----
      if (tid < 64) {
        const unsigned int* sp = slots + tid;
        unsigned int v;
        do {
          asm volatile("global_load_dword %0, %1, off sc0 sc1\n\t"
                       "s_waitcnt vmcnt(0)"
                       : "=v"(v) : "v"(sp) : "memory");
        } while (__any(v < (unsigned int)t));
      }
      __syncthreads();
      // ---- stage h(t-1) from parity buffer (t-1)&1 via IC-coherent loads ----
      {
        const h16* hs = hbuf + (size_t)((t - 1) & 1) * HSTRIDE + (size_t)r0 * HH;
#pragma unroll
        for (int half = 0; half < 2; ++half) {
          u32x4 tmp[8];
#pragma unroll
          for (int j = 0; j < 8; ++j) {
            int c = tid + (half * 8 + j) * 512;   // 0..8191
            int r = c >> 7, col = c & 127;
            const h16* p = hs + (size_t)r * HH + col * 8;
            asm volatile("global_load_dwordx4 %0, %1, off sc0 sc1"
                         : "=v"(tmp[j]) : "v"(p) : "memory");
          }
          asm volatile("s_waitcnt vmcnt(0)" ::: "memory");
#pragma unroll
          for (int j = 0; j < 8; ++j) {
            int c = tid + (half * 8 + j) * 512;
            int r = c >> 7, col = c & 127;
            *(u32x4*)(Abuf + r * KPADH + col * 8) = tmp[j];
          }
        }
      }
      __syncthreads();
      // ---- h-part GEMM: ds_read + MFMA only (B in registers) ----
#pragma unroll
      for (int kk = 0; kk < HH / 32; ++kk) {
        h16x8 a0 = *(const h16x8*)(Abuf + aBase0 + kk * 32);
        h16x8 a1 = *(const h16x8*)(Abuf + aBase1 + kk * 32);
        acc[0] = __builtin_amdgcn_mfma_f32_16x16x32_f16(a0, wh[kk], acc[0], 0, 0, 0);
        acc[1] = __builtin_amdgcn_mfma_f32_16x16x32_f16(a1, wh[kk], acc[1], 0, 0, 0);
      }
    }

    // ---- epilogue: preacts -> LDS (cross-wave gate exchange) ----
#pragma unroll
    for (int mt = 0; mt < 2; ++mt) {
#pragma unroll
      for (int i = 0; i < 4; ++i) {
        int row = mh + mt * 16 + lq * 4 + i;
        Pre[(g * 64 + row) * 17 + lm] = acc[mt][i];
      }
    }
    __syncthreads();
    // ---- elementwise c/h update (c persistent in regs), write h to buf[t&1] ----
    {
      float hv[2];
#pragma unroll
      for (int cc = 0; cc < 2; ++cc) {
        int col = ucolp + cc;
        float fp = Pre[(0 * 64 + urow) * 17 + col];
        float ip = Pre[(1 * 64 + urow) * 17 + col];
        float op = Pre[(2 * 64 + urow) * 17 + col];
        float cp = Pre[(3 * 64 + urow) * 17 + col];
        float c2 = sigm(fp) * cst[cc] + sigm(ip) * tanh_(cp);
        cst[cc] = c2;
        hv[cc] = sigm(op) * tanh_(c2);
      }
      union { h16 h[2]; unsigned int u; } pk;
      pk.h[0] = (h16)hv[0]; pk.h[1] = (h16)hv[1];
      const h16* hp = hbuf + (size_t)(t & 1) * HSTRIDE + (size_t)(r0 + urow) * HH + hc0 + ucolp;
      asm volatile("global_store_dword %0, %1, off sc0 sc1"
                   :: "v"(hp), "v"(pk.u) : "memory");
    }
    __builtin_amdgcn_s_waitcnt(0);   // h stores complete (at IC; they bypass L2)
    __syncthreads();                 // ...for ALL waves of this WG
    if (tid == 0) {                  // publish: plain store, no RMW
      unsigned int val = (unsigned int)(t + 1);
      asm volatile("global_store_dword %0, %1, off sc0 sc1"
                   :: "v"(myslot), "v"(val) : "memory");
    }
  }
}

// ---------------- head: relu -> [64] relu -> [10] softmax ----------------
// reads h(T-1) from parity buffer (T-1)&1 = 1
__global__ void k_head(const h16* __restrict__ hbuf, const float* __restrict__ W1T,
                       const float* __restrict__ b1, const float* __restrict__ W2,
                       const float* __restrict__ b2, float* __restrict__ out)
{
  __shared__ float hrow[1024];
  __shared__ float part[64][5];
  __shared__ float h1[64];
  __shared__ float logit[10];
  int r = blockIdx.x, tid = threadIdx.x;
  for (int i = tid; i < 1024; i += 256) {
    float v = (float)hbuf[(size_t)r * HH + i];
    hrow[i] = v > 0.f ? v : 0.f;
  }
  __syncthreads();
  int n = tid & 63, q = tid >> 6;
  float s = 0.f;
  for (int i = 0; i < 256; ++i) s += hrow[q * 256 + i] * W1T[(q * 256 + i) * 64 + n];
  part[n][q] = s;
  __syncthreads();
  if (tid < 64) {
    float v = part[tid][0] + part[tid][1] + part[tid][2] + part[tid][3] + b1[tid];
    h1[tid] = v > 0.f ? v : 0.f;
  }
  __syncthreads();
  if (tid < 10) {
    float s2 = b2[tid];
    for (int k = 0; k < 64; ++k) s2 += h1[k] * W2[tid * 64 + k];
    logit[tid] = s2;
  }
  __syncthreads();
  if (tid < 10) {
    float m = logit[0];
    for (int i = 1; i < 10; ++i) m = fmaxf(m, logit[i]);
    float sum = 0.f;
    for (int i = 0; i < 10; ++i) sum += __expf(logit[i] - m);
    out[r * 10 + tid] = __expf(logit[tid] - m) / sum;
  }
}

extern "C" void kernel_launch(void* const* d_in, const int* in_sizes, int n_in,
                              void* d_out, int out_size, void* d_ws, size_t ws_size,
                              hipStream_t stream) {
  const float* x   = (const float*)d_in[0];
  const float* Wfx = (const float*)d_in[1];
  const float* Wfh = (const float*)d_in[2];
  const float* bf  = (const float*)d_in[3];
  const float* Wix = (const float*)d_in[4];
  const float* Wih = (const float*)d_in[5];
  const float* bi  = (const float*)d_in[6];
  const float* Wox = (const float*)d_in[7];
  const float* Woh = (const float*)d_in[8];
  const float* bo  = (const float*)d_in[9];
  const float* Wcx = (const float*)d_in[10];
  const float* Wch = (const float*)d_in[11];
  const float* bc  = (const float*)d_in[12];
  const float* W1  = (const float*)d_in[13];
  const float* b1  = (const float*)d_in[14];
  const float* W2  = (const float*)d_in[15];
  const float* b2  = (const float*)d_in[16];
  (void)in_sizes; (void)n_in; (void)out_size;

  char* ws = (char*)d_ws;
  h16* Wx = (h16*)(ws + WX_OFF);
  h16* Wh = (h16*)(ws + WH_OFF);
  float* bias = (float*)(ws + BIAS_OFF);
  float* W1T = (float*)(ws + W1T_OFF);
  h16* hbuf = (h16*)(ws + HBUF_OFF);
  unsigned int* arr = (unsigned int*)(ws + ARR_OFF);
  h16* xh = (h16*)(ws + XH_OFF);
  const int use_xh = (ws_size >= XH_END) ? 1 : 0;

  hipMemsetAsync(arr, 0, 4096, stream);
  k_prep<<<4096, 256, 0, stream>>>(Wfx, Wfh, bf, Wix, Wih, bi, Wox, Woh, bo, Wcx, Wch, bc, W1,
                                   Wx, Wh, bias, W1T);
  if (use_xh) k_castx<<<8192, 256, 0, stream>>>(x, xh);

  (void)hipFuncSetAttribute(reinterpret_cast<const void*>(&k_lstm<1>),
                            hipFuncAttributeMaxDynamicSharedMemorySize, SMEM_BYTES);
  (void)hipFuncSetAttribute(reinterpret_cast<const void*>(&k_lstm<0>),
                            hipFuncAttributeMaxDynamicSharedMemorySize, SMEM_BYTES);
  if (use_xh)
    k_lstm<1><<<256, 512, SMEM_BYTES, stream>>>(x, xh, Wx, Wh, bias, hbuf, arr);
  else
    k_lstm<0><<<256, 512, SMEM_BYTES, stream>>>(x, xh, Wx, Wh, bias, hbuf, arr);

  // h(T-1) lives in parity buffer (TT-1)&1 == 1
  k_head<<<256, 256, 0, stream>>>(hbuf + HSTRIDE, W1T, b1, W2, b2, (float*)d_out);
}